// Round 1
// baseline (3638.228 us; speedup 1.0000x reference)
//
#include <hip/hip_runtime.h>

typedef __attribute__((ext_vector_type(8))) short bf16x8;
typedef __attribute__((ext_vector_type(4))) float f32x4;

__device__ __forceinline__ unsigned short f2bf(float x){
  union { float f; unsigned u; } v; v.f = x;
  unsigned r = v.u + 0x7FFFu + ((v.u >> 16) & 1u);
  return (unsigned short)(r >> 16);
}

// ---------------- embed + mask + counter reset ----------------
__global__ void embed_kernel(const int* __restrict__ seqs, const float* __restrict__ emb,
                             unsigned short* __restrict__ x, int* __restrict__ mask,
                             int* __restrict__ cnt){
  const int t = blockIdx.x, b = blockIdx.y, l = threadIdx.x;
  if (t == 0 && b == 0 && l == 0){ cnt[0] = 0; cnt[1] = 0; }
  const int tok = seqs[b*130 + t];
  if (l == 0) mask[b*130 + t] = (tok != 0) ? 1 : 0;
  const float* src = emb + (size_t)tok * 256;
  unsigned short* dst = x + ((size_t)b*130 + t)*256;
  #pragma unroll
  for (int j = 0; j < 4; ++j) dst[l + j*64] = f2bf(src[l + j*64]);
}

// ---------------- fp32 [R,C] -> bf16 [C,R] transpose ----------------
__global__ void transpose_bf16(const float* __restrict__ in, unsigned short* __restrict__ out,
                               int R, int C){
  __shared__ float tile[32][33];
  const int c0 = blockIdx.x*32, r0 = blockIdx.y*32;
  const int tx = threadIdx.x, ty = threadIdx.y;
  #pragma unroll
  for (int j = 0; j < 32; j += 8) tile[ty+j][tx] = in[(size_t)(r0+ty+j)*C + (c0+tx)];
  __syncthreads();
  #pragma unroll
  for (int j = 0; j < 32; j += 8) out[(size_t)(c0+ty+j)*R + (r0+tx)] = f2bf(tile[tx][ty+j]);
}

// ---------------- persistent pipelined 2-layer LSTM (both dirs) ----------------
// 64 WGs x 512 thr. wg: dir=wg>>5, layer=(wg>>4)&1, u-slice=(wg&15)*32.
// Each wave (8/WG) owns 16 z-columns: gate=(w>>1), half=(w&1).
// Weights live in registers as MFMA B-fragments. Grid barrier per direction.
__global__ __launch_bounds__(512, 2) void lstm_coop(
    const unsigned short* __restrict__ x, const int* __restrict__ maskg,
    const unsigned short* __restrict__ fk0T, const unsigned short* __restrict__ fr0T,
    const unsigned short* __restrict__ fk1T, const unsigned short* __restrict__ fr1T,
    const unsigned short* __restrict__ bk0T, const unsigned short* __restrict__ br0T,
    const unsigned short* __restrict__ bk1T, const unsigned short* __restrict__ br1T,
    const float* __restrict__ fb0, const float* __restrict__ fb1,
    const float* __restrict__ bb0, const float* __restrict__ bb1,
    unsigned short* h0f, unsigned short* h0b,
    unsigned short* aproj, int* cnt)
{
  const int wg = blockIdx.x;
  const int dir = wg >> 5;
  const int layer = (wg >> 4) & 1;
  const int u0 = (wg & 15) * 32;
  const int tid = threadIdx.x;
  const int w = tid >> 6, l = tid & 63;
  const int gate = w >> 1, half = w & 1;
  const int lr = l & 15, lk = l >> 4;
  const int cglob = gate*512 + u0 + half*16 + lr;   // z-column this lane's B-frag covers

  const unsigned short* kT = (layer == 0) ? (dir ? bk0T : fk0T) : (dir ? bk1T : fk1T);
  const unsigned short* rT = (layer == 0) ? (dir ? br0T : fr0T) : (dir ? br1T : fr1T);
  const float* bias = (layer == 0) ? (dir ? bb0 : fb0) : (dir ? bb1 : fb1);
  unsigned short* h0 = dir ? h0b : h0f;
  int* mycnt = cnt + dir;

  // B-fragment weight registers: rT/kT are [2048][K] bf16, K-contiguous.
  bf16x8 wreg[16], kreg[16];
  #pragma unroll
  for (int i = 0; i < 16; ++i)
    wreg[i] = *(const bf16x8*)(rT + (size_t)cglob*512 + i*32 + lk*8);
  if (layer == 0){
    #pragma unroll
    for (int i = 0; i < 8; ++i)
      kreg[i] = *(const bf16x8*)(kT + (size_t)cglob*256 + i*32 + lk*8);
  } else {
    #pragma unroll
    for (int i = 0; i < 16; ++i)
      kreg[i] = *(const bf16x8*)(kT + (size_t)cglob*512 + i*32 + lk*8);
  }

  __shared__ float z_lds[4][16][32];
  __shared__ int mask_s[16*130];
  for (int i = tid; i < 16*130; i += 512) mask_s[i] = maskg[i];

  float c_reg = 0.f, h_reg = 0.f;
  const int gu = tid & 31, gb = tid >> 5;     // gate-phase (u, b) ownership
  const float bzi = bias[u0+gu], bzf = bias[512 + u0+gu];
  const float bzc = bias[1024 + u0+gu], bzo = bias[1536 + u0+gu];
  __syncthreads();

  for (int it = 0; it < 129; ++it){
    const int t = (layer == 0) ? it : it - 1;
    const bool act = (layer == 0) ? (it < 128) : (it >= 1);
    if (act){
      f32x4 acc = {0.f, 0.f, 0.f, 0.f};
      if (layer == 0){
        const int pos = dir ? (129 - t) : t;
        const unsigned short* xa = x + ((size_t)lr*130 + pos)*256 + lk*8;
        #pragma unroll
        for (int i = 0; i < 8; ++i){
          bf16x8 a = *(const bf16x8*)(xa + i*32);
          acc = __builtin_amdgcn_mfma_f32_16x16x32_bf16(a, kreg[i], acc, 0, 0, 0);
        }
      } else {
        const unsigned short* xa = h0 + ((size_t)t*16 + lr)*512 + lk*8;
        #pragma unroll
        for (int i = 0; i < 16; ++i){
          bf16x8 a = *(const bf16x8*)(xa + i*32);
          acc = __builtin_amdgcn_mfma_f32_16x16x32_bf16(a, kreg[i], acc, 0, 0, 0);
        }
      }
      if (t > 0){
        const unsigned short* ha;
        if (layer == 0) ha = h0 + ((size_t)(t-1)*16 + lr)*512 + lk*8;
        else {
          const int prow = dir ? (128 - t) : (t - 1);
          ha = aproj + ((size_t)lr*128 + prow)*1024 + dir*512 + lk*8;
        }
        #pragma unroll
        for (int i = 0; i < 16; ++i){
          bf16x8 a = *(const bf16x8*)(ha + i*32);
          acc = __builtin_amdgcn_mfma_f32_16x16x32_bf16(a, wreg[i], acc, 0, 0, 0);
        }
      }
      // C-frag: col = lane&15, row = (lane>>4)*4 + r  (verified m89/m91)
      #pragma unroll
      for (int r = 0; r < 4; ++r) z_lds[gate][lk*4 + r][half*16 + lr] = acc[r];
    }
    __syncthreads();
    if (act){
      const float zi = z_lds[0][gb][gu] + bzi;
      const float zf = z_lds[1][gb][gu] + bzf;
      const float zc = z_lds[2][gb][gu] + bzc;
      const float zo = z_lds[3][gb][gu] + bzo;
      const float iv = 1.f / (1.f + expf(-zi));
      const float fv = 1.f / (1.f + expf(-zf));
      const float ov = 1.f / (1.f + expf(-zo));
      const float gv = tanhf(zc);
      float cn = fv*c_reg + iv*gv;
      float hn = ov*tanhf(cn);
      const int pos = dir ? (129 - t) : t;
      if (mask_s[gb*130 + pos] == 0){ cn = c_reg; hn = h_reg; }
      c_reg = cn; h_reg = hn;
      const unsigned short hb = f2bf(hn);
      if (layer == 0) h0[((size_t)t*16 + gb)*512 + u0 + gu] = hb;
      else {
        const int row = dir ? (127 - t) : t;
        aproj[((size_t)gb*128 + row)*1024 + dir*512 + u0 + gu] = hb;
      }
    }
    // ---- per-direction grid barrier (release/acquire) ----
    __threadfence();
    __syncthreads();
    if (tid == 0){
      __hip_atomic_fetch_add(mycnt, 1, __ATOMIC_RELAXED, __HIP_MEMORY_SCOPE_AGENT);
      const int target = 32*(it + 1);
      while (__hip_atomic_load(mycnt, __ATOMIC_RELAXED, __HIP_MEMORY_SCOPE_AGENT) < target)
        __builtin_amdgcn_s_sleep(1);
    }
    __syncthreads();
    __threadfence();
  }
}

// ---------------- bf16 MFMA GEMM: C[M,N] = A[M,K] * Bt[N,K]^T + bias ----------------
// 128x128 tile, BK=32, 4 waves (2x2 of 64x64), XOR-swizzled LDS (write & read sides).
__global__ __launch_bounds__(256) void gemm_bf16(
    const unsigned short* __restrict__ A, const unsigned short* __restrict__ Bt,
    const float* __restrict__ bias, float* __restrict__ C,
    int M, int N, int K)
{
  __shared__ unsigned short lA[128*32], lB[128*32];
  const int tid = threadIdx.x;
  const int w = tid >> 6, l = tid & 63;
  const int wr = w >> 1, wc = w & 1;
  const int lr = l & 15, lk = l >> 4;
  const int brow = blockIdx.y * 128, bcol = blockIdx.x * 128;
  f32x4 acc[4][4] = {};
  for (int k0 = 0; k0 < K; k0 += 32){
    __syncthreads();
    #pragma unroll
    for (int c = 0; c < 2; ++c){
      const int L = (tid + c*256) * 16;          // logical byte in 8KB tile
      const int row = L >> 6;
      const int kb = L & 63;
      const int sp = L ^ (((L >> 7) & 3) << 4);  // involutive swizzle
      *(int4*)((char*)lA + sp) = *(const int4*)((const char*)(A + (size_t)(brow+row)*K + k0) + kb);
      *(int4*)((char*)lB + sp) = *(const int4*)((const char*)(Bt + (size_t)(bcol+row)*K + k0) + kb);
    }
    __syncthreads();
    bf16x8 af[4], bfr[4];
    #pragma unroll
    for (int m = 0; m < 4; ++m){
      const int L = (wr*64 + m*16 + lr)*64 + lk*16;
      const int sp = L ^ (((L >> 7) & 3) << 4);
      af[m] = *(const bf16x8*)((char*)lA + sp);
    }
    #pragma unroll
    for (int n = 0; n < 4; ++n){
      const int L = (wc*64 + n*16 + lr)*64 + lk*16;
      const int sp = L ^ (((L >> 7) & 3) << 4);
      bfr[n] = *(const bf16x8*)((char*)lB + sp);
    }
    #pragma unroll
    for (int m = 0; m < 4; ++m)
      #pragma unroll
      for (int n = 0; n < 4; ++n)
        acc[m][n] = __builtin_amdgcn_mfma_f32_16x16x32_bf16(af[m], bfr[n], acc[m][n], 0, 0, 0);
  }
  #pragma unroll
  for (int m = 0; m < 4; ++m){
    #pragma unroll
    for (int n = 0; n < 4; ++n){
      const int col = bcol + wc*64 + n*16 + lr;
      const float bv = bias[col];
      const int row0 = brow + wr*64 + m*16 + lk*4;
      #pragma unroll
      for (int r = 0; r < 4; ++r)
        C[(size_t)(row0 + r)*N + col] = acc[m][n][r] + bv;
    }
  }
}

extern "C" void kernel_launch(void* const* d_in, const int* in_sizes, int n_in,
                              void* d_out, int out_size, void* d_ws, size_t ws_size,
                              hipStream_t stream){
  (void)in_sizes; (void)n_in; (void)out_size; (void)ws_size;
  const int*   seqs = (const int*)d_in[0];
  const float* emb  = (const float*)d_in[1];
  const float* fk0  = (const float*)d_in[2];
  const float* fr0  = (const float*)d_in[3];
  const float* fb0  = (const float*)d_in[4];
  const float* fk1  = (const float*)d_in[5];
  const float* fr1  = (const float*)d_in[6];
  const float* fb1  = (const float*)d_in[7];
  const float* bk0  = (const float*)d_in[8];
  const float* br0  = (const float*)d_in[9];
  const float* bb0  = (const float*)d_in[10];
  const float* bk1  = (const float*)d_in[11];
  const float* br1  = (const float*)d_in[12];
  const float* bb1  = (const float*)d_in[13];
  const float* Wp   = (const float*)d_in[14];
  const float* bp   = (const float*)d_in[15];
  float* out = (float*)d_out;

  char* ws = (char*)d_ws;
  size_t off = 0;
  auto alloc = [&](size_t b){ size_t o = off; off += (b + 255) & ~(size_t)255; return o; };
  int* cnt              = (int*)(ws + alloc(8));
  unsigned short* x     = (unsigned short*)(ws + alloc((size_t)16*130*256*2));
  int* mask             = (int*)(ws + alloc((size_t)16*130*4));
  unsigned short* fk0T  = (unsigned short*)(ws + alloc((size_t)2048*256*2));
  unsigned short* fr0T  = (unsigned short*)(ws + alloc((size_t)2048*512*2));
  unsigned short* fk1T  = (unsigned short*)(ws + alloc((size_t)2048*512*2));
  unsigned short* fr1T  = (unsigned short*)(ws + alloc((size_t)2048*512*2));
  unsigned short* bk0T  = (unsigned short*)(ws + alloc((size_t)2048*256*2));
  unsigned short* br0T  = (unsigned short*)(ws + alloc((size_t)2048*512*2));
  unsigned short* bk1T  = (unsigned short*)(ws + alloc((size_t)2048*512*2));
  unsigned short* br1T  = (unsigned short*)(ws + alloc((size_t)2048*512*2));
  unsigned short* h0f   = (unsigned short*)(ws + alloc((size_t)128*16*512*2));
  unsigned short* h0b   = (unsigned short*)(ws + alloc((size_t)128*16*512*2));
  unsigned short* aproj = (unsigned short*)(ws + alloc((size_t)2048*1024*2));
  unsigned short* WpT   = (unsigned short*)(ws + alloc((size_t)32000*1024*2));

  embed_kernel<<<dim3(130,16), 64, 0, stream>>>(seqs, emb, x, mask, cnt);

  dim3 tb(32, 8);
  transpose_bf16<<<dim3(64, 8),   tb, 0, stream>>>(fk0, fk0T, 256, 2048);
  transpose_bf16<<<dim3(64, 16),  tb, 0, stream>>>(fr0, fr0T, 512, 2048);
  transpose_bf16<<<dim3(64, 16),  tb, 0, stream>>>(fk1, fk1T, 512, 2048);
  transpose_bf16<<<dim3(64, 16),  tb, 0, stream>>>(fr1, fr1T, 512, 2048);
  transpose_bf16<<<dim3(64, 8),   tb, 0, stream>>>(bk0, bk0T, 256, 2048);
  transpose_bf16<<<dim3(64, 16),  tb, 0, stream>>>(br0, br0T, 512, 2048);
  transpose_bf16<<<dim3(64, 16),  tb, 0, stream>>>(bk1, bk1T, 512, 2048);
  transpose_bf16<<<dim3(64, 16),  tb, 0, stream>>>(br1, br1T, 512, 2048);
  transpose_bf16<<<dim3(1000, 32), tb, 0, stream>>>(Wp, WpT, 1024, 32000);

  lstm_coop<<<64, 512, 0, stream>>>(x, mask,
      fk0T, fr0T, fk1T, fr1T, bk0T, br0T, bk1T, br1T,
      fb0, fb1, bb0, bb1, h0f, h0b, aproj, cnt);

  gemm_bf16<<<dim3(250, 16), 256, 0, stream>>>(aproj, WpT, bp, out, 2048, 32000, 1024);
}

// Round 2
// 1508.131 us; speedup vs baseline: 2.4124x; 2.4124x over previous
//
#include <hip/hip_runtime.h>

typedef __attribute__((ext_vector_type(8))) short bf16x8;
typedef __attribute__((ext_vector_type(4))) float f32x4;

__device__ __forceinline__ unsigned short f2bf(float x){
  union { float f; unsigned u; } v; v.f = x;
  unsigned r = v.u + 0x7FFFu + ((v.u >> 16) & 1u);
  return (unsigned short)(r >> 16);
}

// Cache-bypass (coherence-point) accessors: sc0 = bypass L1, sc1 = bypass L2.
// Needed because per-XCD L2s are not coherent; bypassing both means no fences.
#define BYPASS_LD(dst, base, OFF) \
  asm volatile("global_load_dwordx4 %0, %1, off offset:" #OFF " sc0 sc1" \
               : "=v"(dst) : "v"(base))
#define LD16(S, B) do{ \
  BYPASS_LD(S[0],B,0);    BYPASS_LD(S[1],B,64);   BYPASS_LD(S[2],B,128);  BYPASS_LD(S[3],B,192); \
  BYPASS_LD(S[4],B,256);  BYPASS_LD(S[5],B,320);  BYPASS_LD(S[6],B,384);  BYPASS_LD(S[7],B,448); \
  BYPASS_LD(S[8],B,512);  BYPASS_LD(S[9],B,576);  BYPASS_LD(S[10],B,640); BYPASS_LD(S[11],B,704); \
  BYPASS_LD(S[12],B,768); BYPASS_LD(S[13],B,832); BYPASS_LD(S[14],B,896); BYPASS_LD(S[15],B,960); \
}while(0)
#define WAIT_VM0() do{ asm volatile("s_waitcnt vmcnt(0)" ::: "memory"); \
                       __builtin_amdgcn_sched_barrier(0); }while(0)
#define BYPASS_ST_SHORT(base, val) \
  asm volatile("global_store_short %0, %1, off sc0 sc1" :: "v"(base), "v"(val))

// ---------------- embed + mask + counter reset ----------------
__global__ void embed_kernel(const int* __restrict__ seqs, const float* __restrict__ emb,
                             unsigned short* __restrict__ x, int* __restrict__ mask,
                             int* __restrict__ cnt){
  const int t = blockIdx.x, b = blockIdx.y, l = threadIdx.x;
  if (t == 0 && b == 0 && l == 0){ cnt[0] = 0; cnt[1] = 0; cnt[2] = 0; cnt[3] = 0; }
  const int tok = seqs[b*130 + t];
  if (l == 0) mask[b*130 + t] = (tok != 0) ? 1 : 0;
  const float* src = emb + (size_t)tok * 256;
  unsigned short* dst = x + ((size_t)b*130 + t)*256;
  #pragma unroll
  for (int j = 0; j < 4; ++j) dst[l + j*64] = f2bf(src[l + j*64]);
}

// ---------------- fp32 [R,C] -> bf16 [C,R] transpose ----------------
__global__ void transpose_bf16(const float* __restrict__ in, unsigned short* __restrict__ out,
                               int R, int C){
  __shared__ float tile[32][33];
  const int c0 = blockIdx.x*32, r0 = blockIdx.y*32;
  const int tx = threadIdx.x, ty = threadIdx.y;
  #pragma unroll
  for (int j = 0; j < 32; j += 8) tile[ty+j][tx] = in[(size_t)(r0+ty+j)*C + (c0+tx)];
  __syncthreads();
  #pragma unroll
  for (int j = 0; j < 32; j += 8) out[(size_t)(c0+ty+j)*R + (r0+tx)] = f2bf(tile[tx][ty+j]);
}

// ---------------- persistent pipelined 2-layer LSTM (both dirs) ----------------
// 64 WGs x 512 thr. wg: dir=wg>>5, layer=(wg>>4)&1, u-slice=(wg&15)*32.
// Weights in registers as MFMA B-fragments. Communication: cache-bypass stores
// + loads (sc0 sc1 -> Infinity-Cache coherence point). Sync: per-(dir,layer)
// monotonic counters, one-way (layer1 polls layer0; layer0 never waits on layer1).
__global__ __launch_bounds__(512, 2) void lstm_coop(
    const unsigned short* __restrict__ x, const int* __restrict__ maskg,
    const unsigned short* __restrict__ fk0T, const unsigned short* __restrict__ fr0T,
    const unsigned short* __restrict__ fk1T, const unsigned short* __restrict__ fr1T,
    const unsigned short* __restrict__ bk0T, const unsigned short* __restrict__ br0T,
    const unsigned short* __restrict__ bk1T, const unsigned short* __restrict__ br1T,
    const float* __restrict__ fb0, const float* __restrict__ fb1,
    const float* __restrict__ bb0, const float* __restrict__ bb1,
    unsigned short* h0f, unsigned short* h0b,
    unsigned short* aproj, int* cnt)
{
  const int wg = blockIdx.x;
  const int dir = wg >> 5;
  const int layer = (wg >> 4) & 1;
  const int u0 = (wg & 15) * 32;
  const int tid = threadIdx.x;
  const int w = tid >> 6, l = tid & 63;
  const int gate = w >> 1, half = w & 1;
  const int lr = l & 15, lk = l >> 4;
  const int cglob = gate*512 + u0 + half*16 + lr;   // z-column this lane's B-frag covers

  const unsigned short* kT = (layer == 0) ? (dir ? bk0T : fk0T) : (dir ? bk1T : fk1T);
  const unsigned short* rT = (layer == 0) ? (dir ? br0T : fr0T) : (dir ? br1T : fr1T);
  const float* bias = (layer == 0) ? (dir ? bb0 : fb0) : (dir ? bb1 : fb1);
  unsigned short* h0 = dir ? h0b : h0f;
  int* c_own = cnt + (layer ? 2 + dir : dir);   // counter this WG increments
  int* c_in  = cnt + dir;                        // producer counter (layer1 only)

  // B-fragment weight registers: rT/kT are [2048][K] bf16, K-contiguous.
  bf16x8 wreg[16], kreg[16];
  #pragma unroll
  for (int i = 0; i < 16; ++i)
    wreg[i] = *(const bf16x8*)(rT + (size_t)cglob*512 + i*32 + lk*8);
  if (layer == 0){
    #pragma unroll
    for (int i = 0; i < 8; ++i)
      kreg[i] = *(const bf16x8*)(kT + (size_t)cglob*256 + i*32 + lk*8);
  } else {
    #pragma unroll
    for (int i = 0; i < 16; ++i)
      kreg[i] = *(const bf16x8*)(kT + (size_t)cglob*512 + i*32 + lk*8);
  }

  __shared__ float z_lds[4][16][32];
  __shared__ int mask_s[16*130];
  for (int i = tid; i < 16*130; i += 512) mask_s[i] = maskg[i];

  float c_reg = 0.f, h_reg = 0.f;
  const int gu = tid & 31, gb = tid >> 5;     // gate-phase (u, b) ownership
  const float bzi = bias[u0+gu], bzf = bias[512 + u0+gu];
  const float bzc = bias[1024 + u0+gu], bzo = bias[1536 + u0+gu];
  __syncthreads();

  for (int t = 0; t < 128; ++t){
    if (layer == 1){
      // wait for h0[t] from all 16 layer-0 peers of this direction
      if (tid == 0){
        while (__hip_atomic_load(c_in, __ATOMIC_RELAXED, __HIP_MEMORY_SCOPE_AGENT) < 16*(t+1))
          __builtin_amdgcn_s_sleep(2);
      }
      __syncthreads();
    }
    f32x4 acc = {0.f, 0.f, 0.f, 0.f};
    bf16x8 st[16];
    if (layer == 0){
      const int pos = dir ? (129 - t) : t;
      const unsigned short* xa = x + ((size_t)lr*130 + pos)*256 + lk*8;
      #pragma unroll
      for (int i = 0; i < 8; ++i){
        bf16x8 a = *(const bf16x8*)(xa + i*32);
        acc = __builtin_amdgcn_mfma_f32_16x16x32_bf16(a, kreg[i], acc, 0, 0, 0);
      }
      if (t > 0){
        const unsigned short* ha = h0 + ((size_t)(t-1)*16 + lr)*512 + lk*8;
        LD16(st, ha);
        WAIT_VM0();
        #pragma unroll
        for (int i = 0; i < 16; ++i)
          acc = __builtin_amdgcn_mfma_f32_16x16x32_bf16(st[i], wreg[i], acc, 0, 0, 0);
      }
    } else {
      const unsigned short* xa = h0 + ((size_t)t*16 + lr)*512 + lk*8;
      LD16(st, xa);
      WAIT_VM0();
      #pragma unroll
      for (int i = 0; i < 16; ++i)
        acc = __builtin_amdgcn_mfma_f32_16x16x32_bf16(st[i], kreg[i], acc, 0, 0, 0);
      if (t > 0){
        const int prow = dir ? (128 - t) : (t - 1);
        const unsigned short* ha = aproj + ((size_t)lr*128 + prow)*1024 + dir*512 + lk*8;
        LD16(st, ha);
        WAIT_VM0();
        #pragma unroll
        for (int i = 0; i < 16; ++i)
          acc = __builtin_amdgcn_mfma_f32_16x16x32_bf16(st[i], wreg[i], acc, 0, 0, 0);
      }
    }
    // C-frag: col = lane&15, row = (lane>>4)*4 + r  (verified m89/m91)
    #pragma unroll
    for (int r = 0; r < 4; ++r) z_lds[gate][lk*4 + r][half*16 + lr] = acc[r];
    __syncthreads();
    {
      const float zi = z_lds[0][gb][gu] + bzi;
      const float zf = z_lds[1][gb][gu] + bzf;
      const float zc = z_lds[2][gb][gu] + bzc;
      const float zo = z_lds[3][gb][gu] + bzo;
      const float iv = 1.f / (1.f + expf(-zi));
      const float fv = 1.f / (1.f + expf(-zf));
      const float ov = 1.f / (1.f + expf(-zo));
      const float gv = tanhf(zc);
      float cn = fv*c_reg + iv*gv;
      float hn = ov*tanhf(cn);
      const int pos = dir ? (129 - t) : t;
      if (mask_s[gb*130 + pos] == 0){ cn = c_reg; hn = h_reg; }
      c_reg = cn; h_reg = hn;
      const unsigned short hb = f2bf(hn);
      if (layer == 0){
        unsigned short* p = h0 + ((size_t)t*16 + gb)*512 + u0 + gu;
        BYPASS_ST_SHORT(p, (unsigned)hb);
      } else {
        const int row = dir ? (127 - t) : t;
        unsigned short* p = aproj + ((size_t)gb*128 + row)*1024 + dir*512 + u0 + gu;
        BYPASS_ST_SHORT(p, (unsigned)hb);
      }
    }
    // drain own stores to coherence point in EVERY wave, then publish
    asm volatile("s_waitcnt vmcnt(0)" ::: "memory");
    __syncthreads();
    if (tid == 0){
      __hip_atomic_fetch_add(c_own, 1, __ATOMIC_RELAXED, __HIP_MEMORY_SCOPE_AGENT);
      // wait for own-layer peers (recurrence input for step t+1)
      while (__hip_atomic_load(c_own, __ATOMIC_RELAXED, __HIP_MEMORY_SCOPE_AGENT) < 16*(t+1))
        __builtin_amdgcn_s_sleep(2);
    }
    __syncthreads();
  }
}

// ---------------- bf16 MFMA GEMM: C[M,N] = A[M,K] * Bt[N,K]^T + bias ----------------
// 128x128 tile, BK=32, 4 waves (2x2 of 64x64), XOR-swizzled LDS (write & read sides).
__global__ __launch_bounds__(256) void gemm_bf16(
    const unsigned short* __restrict__ A, const unsigned short* __restrict__ Bt,
    const float* __restrict__ bias, float* __restrict__ C,
    int M, int N, int K)
{
  __shared__ unsigned short lA[128*32], lB[128*32];
  const int tid = threadIdx.x;
  const int w = tid >> 6, l = tid & 63;
  const int wr = w >> 1, wc = w & 1;
  const int lr = l & 15, lk = l >> 4;
  const int brow = blockIdx.y * 128, bcol = blockIdx.x * 128;
  f32x4 acc[4][4] = {};
  for (int k0 = 0; k0 < K; k0 += 32){
    __syncthreads();
    #pragma unroll
    for (int c = 0; c < 2; ++c){
      const int L = (tid + c*256) * 16;          // logical byte in 8KB tile
      const int row = L >> 6;
      const int kb = L & 63;
      const int sp = L ^ (((L >> 7) & 3) << 4);  // involutive swizzle
      *(int4*)((char*)lA + sp) = *(const int4*)((const char*)(A + (size_t)(brow+row)*K + k0) + kb);
      *(int4*)((char*)lB + sp) = *(const int4*)((const char*)(Bt + (size_t)(bcol+row)*K + k0) + kb);
    }
    __syncthreads();
    bf16x8 af[4], bfr[4];
    #pragma unroll
    for (int m = 0; m < 4; ++m){
      const int L = (wr*64 + m*16 + lr)*64 + lk*16;
      const int sp = L ^ (((L >> 7) & 3) << 4);
      af[m] = *(const bf16x8*)((char*)lA + sp);
    }
    #pragma unroll
    for (int n = 0; n < 4; ++n){
      const int L = (wc*64 + n*16 + lr)*64 + lk*16;
      const int sp = L ^ (((L >> 7) & 3) << 4);
      bfr[n] = *(const bf16x8*)((char*)lB + sp);
    }
    #pragma unroll
    for (int m = 0; m < 4; ++m)
      #pragma unroll
      for (int n = 0; n < 4; ++n)
        acc[m][n] = __builtin_amdgcn_mfma_f32_16x16x32_bf16(af[m], bfr[n], acc[m][n], 0, 0, 0);
  }
  #pragma unroll
  for (int m = 0; m < 4; ++m){
    #pragma unroll
    for (int n = 0; n < 4; ++n){
      const int col = bcol + wc*64 + n*16 + lr;
      const float bv = bias[col];
      const int row0 = brow + wr*64 + m*16 + lk*4;
      #pragma unroll
      for (int r = 0; r < 4; ++r)
        C[(size_t)(row0 + r)*N + col] = acc[m][n][r] + bv;
    }
  }
}

extern "C" void kernel_launch(void* const* d_in, const int* in_sizes, int n_in,
                              void* d_out, int out_size, void* d_ws, size_t ws_size,
                              hipStream_t stream){
  (void)in_sizes; (void)n_in; (void)out_size; (void)ws_size;
  const int*   seqs = (const int*)d_in[0];
  const float* emb  = (const float*)d_in[1];
  const float* fk0  = (const float*)d_in[2];
  const float* fr0  = (const float*)d_in[3];
  const float* fb0  = (const float*)d_in[4];
  const float* fk1  = (const float*)d_in[5];
  const float* fr1  = (const float*)d_in[6];
  const float* fb1  = (const float*)d_in[7];
  const float* bk0  = (const float*)d_in[8];
  const float* br0  = (const float*)d_in[9];
  const float* bb0  = (const float*)d_in[10];
  const float* bk1  = (const float*)d_in[11];
  const float* br1  = (const float*)d_in[12];
  const float* bb1  = (const float*)d_in[13];
  const float* Wp   = (const float*)d_in[14];
  const float* bp   = (const float*)d_in[15];
  float* out = (float*)d_out;

  char* ws = (char*)d_ws;
  size_t off = 0;
  auto alloc = [&](size_t b){ size_t o = off; off += (b + 255) & ~(size_t)255; return o; };
  int* cnt              = (int*)(ws + alloc(16));
  unsigned short* x     = (unsigned short*)(ws + alloc((size_t)16*130*256*2));
  int* mask             = (int*)(ws + alloc((size_t)16*130*4));
  unsigned short* fk0T  = (unsigned short*)(ws + alloc((size_t)2048*256*2));
  unsigned short* fr0T  = (unsigned short*)(ws + alloc((size_t)2048*512*2));
  unsigned short* fk1T  = (unsigned short*)(ws + alloc((size_t)2048*512*2));
  unsigned short* fr1T  = (unsigned short*)(ws + alloc((size_t)2048*512*2));
  unsigned short* bk0T  = (unsigned short*)(ws + alloc((size_t)2048*256*2));
  unsigned short* br0T  = (unsigned short*)(ws + alloc((size_t)2048*512*2));
  unsigned short* bk1T  = (unsigned short*)(ws + alloc((size_t)2048*512*2));
  unsigned short* br1T  = (unsigned short*)(ws + alloc((size_t)2048*512*2));
  unsigned short* h0f   = (unsigned short*)(ws + alloc((size_t)128*16*512*2));
  unsigned short* h0b   = (unsigned short*)(ws + alloc((size_t)128*16*512*2));
  unsigned short* aproj = (unsigned short*)(ws + alloc((size_t)2048*1024*2));
  unsigned short* WpT   = (unsigned short*)(ws + alloc((size_t)32000*1024*2));

  embed_kernel<<<dim3(130,16), 64, 0, stream>>>(seqs, emb, x, mask, cnt);

  dim3 tb(32, 8);
  transpose_bf16<<<dim3(64, 8),   tb, 0, stream>>>(fk0, fk0T, 256, 2048);
  transpose_bf16<<<dim3(64, 16),  tb, 0, stream>>>(fr0, fr0T, 512, 2048);
  transpose_bf16<<<dim3(64, 16),  tb, 0, stream>>>(fk1, fk1T, 512, 2048);
  transpose_bf16<<<dim3(64, 16),  tb, 0, stream>>>(fr1, fr1T, 512, 2048);
  transpose_bf16<<<dim3(64, 8),   tb, 0, stream>>>(bk0, bk0T, 256, 2048);
  transpose_bf16<<<dim3(64, 16),  tb, 0, stream>>>(br0, br0T, 512, 2048);
  transpose_bf16<<<dim3(64, 16),  tb, 0, stream>>>(bk1, bk1T, 512, 2048);
  transpose_bf16<<<dim3(64, 16),  tb, 0, stream>>>(br1, br1T, 512, 2048);
  transpose_bf16<<<dim3(1000, 32), tb, 0, stream>>>(Wp, WpT, 1024, 32000);

  lstm_coop<<<64, 512, 0, stream>>>(x, mask,
      fk0T, fr0T, fk1T, fr1T, bk0T, br0T, bk1T, br1T,
      fb0, fb1, bb0, bb1, h0f, h0b, aproj, cnt);

  gemm_bf16<<<dim3(250, 16), 256, 0, stream>>>(aproj, WpT, bp, out, 2048, 32000, 1024);
}

// Round 3
// 1433.454 us; speedup vs baseline: 2.5381x; 1.0521x over previous
//
#include <hip/hip_runtime.h>

typedef __attribute__((ext_vector_type(8))) short bf16x8;
typedef __attribute__((ext_vector_type(4))) float f32x4;

__device__ __forceinline__ unsigned short f2bf(float x){
  union { float f; unsigned u; } v; v.f = x;
  unsigned r = v.u + 0x7FFFu + ((v.u >> 16) & 1u);
  return (unsigned short)(r >> 16);
}

// Cache-bypass (coherence-point) accessors: sc0 = bypass L1, sc1 = bypass L2.
// Per-XCD L2s are not coherent; bypassing both means no fences are ever needed.
#define BYPASS_LD(dst, base, OFF) \
  asm volatile("global_load_dwordx4 %0, %1, off offset:" #OFF " sc0 sc1" \
               : "=v"(dst) : "v"(base))
#define LD16(S, B) do{ \
  BYPASS_LD(S[0],B,0);    BYPASS_LD(S[1],B,64);   BYPASS_LD(S[2],B,128);  BYPASS_LD(S[3],B,192); \
  BYPASS_LD(S[4],B,256);  BYPASS_LD(S[5],B,320);  BYPASS_LD(S[6],B,384);  BYPASS_LD(S[7],B,448); \
  BYPASS_LD(S[8],B,512);  BYPASS_LD(S[9],B,576);  BYPASS_LD(S[10],B,640); BYPASS_LD(S[11],B,704); \
  BYPASS_LD(S[12],B,768); BYPASS_LD(S[13],B,832); BYPASS_LD(S[14],B,896); BYPASS_LD(S[15],B,960); \
}while(0)
#define WAIT_VM0() do{ asm volatile("s_waitcnt vmcnt(0)" ::: "memory"); \
                       __builtin_amdgcn_sched_barrier(0); }while(0)
#define BYPASS_ST_SHORT(base, val) \
  asm volatile("global_store_short %0, %1, off sc0 sc1" :: "v"(base), "v"(val))

__device__ __forceinline__ int ld_flag(const int* p){
  int v;
  asm volatile("global_load_dword %0, %1, off sc0 sc1\n\t"
               "s_waitcnt vmcnt(0)"
               : "=v"(v) : "v"(p) : "memory");
  return v;
}

__device__ __forceinline__ void gload_lds16(const void* g, void* l){
  __builtin_amdgcn_global_load_lds(
      (const __attribute__((address_space(1))) unsigned*)g,
      (__attribute__((address_space(3))) unsigned*)l, 16, 0, 0);
}

// ---------------- embed + mask + flag reset ----------------
__global__ void embed_kernel(const int* __restrict__ seqs, const float* __restrict__ emb,
                             unsigned short* __restrict__ x, int* __restrict__ mask,
                             int* __restrict__ flags){
  const int t = blockIdx.x, b = blockIdx.y, l = threadIdx.x;
  if (t == 0 && b == 0){
    #pragma unroll
    for (int j = 0; j < 16; ++j) flags[l + j*64] = 0;   // 1024 ints = 64 slots x 64B
  }
  const int tok = seqs[b*130 + t];
  if (l == 0) mask[b*130 + t] = (tok != 0) ? 1 : 0;
  const float* src = emb + (size_t)tok * 256;
  unsigned short* dst = x + ((size_t)b*130 + t)*256;
  #pragma unroll
  for (int j = 0; j < 4; ++j) dst[l + j*64] = f2bf(src[l + j*64]);
}

// ---------------- fp32 [R,C] -> bf16 [C,R] transpose ----------------
__global__ void transpose_bf16(const float* __restrict__ in, unsigned short* __restrict__ out,
                               int R, int C){
  __shared__ float tile[32][33];
  const int c0 = blockIdx.x*32, r0 = blockIdx.y*32;
  const int tx = threadIdx.x, ty = threadIdx.y;
  #pragma unroll
  for (int j = 0; j < 32; j += 8) tile[ty+j][tx] = in[(size_t)(r0+ty+j)*C + (c0+tx)];
  __syncthreads();
  #pragma unroll
  for (int j = 0; j < 32; j += 8) out[(size_t)(c0+ty+j)*R + (r0+tx)] = f2bf(tile[tx][ty+j]);
}

// ---------------- persistent pipelined 2-layer LSTM (both dirs) ----------------
// 64 WGs x 512 thr. wg: dir=wg>>5, layer=(wg>>4)&1, u-slice=(wg&15)*32.
// Weights in registers as MFMA B-fragments. Data exchange: cache-bypass (sc0 sc1).
// Sync: per-WG monotonic flag words, one 64B line each (store-release / poll-acquire,
// NO atomic RMW -> no coherence-point line ping-pong).
__global__ __launch_bounds__(512, 2) void lstm_coop(
    const unsigned short* __restrict__ x, const int* __restrict__ maskg,
    const unsigned short* __restrict__ fk0T, const unsigned short* __restrict__ fr0T,
    const unsigned short* __restrict__ fk1T, const unsigned short* __restrict__ fr1T,
    const unsigned short* __restrict__ bk0T, const unsigned short* __restrict__ br0T,
    const unsigned short* __restrict__ bk1T, const unsigned short* __restrict__ br1T,
    const float* __restrict__ fb0, const float* __restrict__ fb1,
    const float* __restrict__ bb0, const float* __restrict__ bb1,
    unsigned short* h0f, unsigned short* h0b,
    unsigned short* aproj, int* flags)
{
  const int wg = blockIdx.x;
  const int dir = wg >> 5;
  const int layer = (wg >> 4) & 1;
  const int u0 = (wg & 15) * 32;
  const int tid = threadIdx.x;
  const int w = tid >> 6, l = tid & 63;
  const int gate = w >> 1, half = w & 1;
  const int lr = l & 15, lk = l >> 4;
  const int cglob = gate*512 + u0 + half*16 + lr;   // z-column this lane's B-frag covers

  const unsigned short* kT = (layer == 0) ? (dir ? bk0T : fk0T) : (dir ? bk1T : fk1T);
  const unsigned short* rT = (layer == 0) ? (dir ? br0T : fr0T) : (dir ? br1T : fr1T);
  const float* bias = (layer == 0) ? (dir ? bb0 : fb0) : (dir ? bb1 : fb1);
  unsigned short* h0 = dir ? h0b : h0f;

  // flag slots: group g = layer*2+dir; slot k at flags + (g*16+k)*16 (64B apart)
  int* fown  = flags + (layer*2 + dir)*256;
  int* fprod = flags + dir*256;                  // layer-0 group of same dir
  int* fself = fown + (wg & 15)*16;

  // B-fragment weight registers: rT/kT are [2048][K] bf16, K-contiguous.
  bf16x8 wreg[16], kreg[16];
  #pragma unroll
  for (int i = 0; i < 16; ++i)
    wreg[i] = *(const bf16x8*)(rT + (size_t)cglob*512 + i*32 + lk*8);
  if (layer == 0){
    #pragma unroll
    for (int i = 0; i < 8; ++i)
      kreg[i] = *(const bf16x8*)(kT + (size_t)cglob*256 + i*32 + lk*8);
  } else {
    #pragma unroll
    for (int i = 0; i < 16; ++i)
      kreg[i] = *(const bf16x8*)(kT + (size_t)cglob*512 + i*32 + lk*8);
  }

  __shared__ float z_lds[4][16][32];
  __shared__ int mask_s[16*130];
  for (int i = tid; i < 16*130; i += 512) mask_s[i] = maskg[i];

  float c_reg = 0.f, h_reg = 0.f;
  const int gu = tid & 31, gb = tid >> 5;     // gate-phase (u, b) ownership
  const float bzi = bias[u0+gu], bzf = bias[512 + u0+gu];
  const float bzc = bias[1024 + u0+gu], bzo = bias[1536 + u0+gu];
  __syncthreads();

  for (int t = 0; t < 128; ++t){
    // ---- acquire: wave 0 polls peer/producer flags (each in its own line) ----
    if (w == 0){
      const int* fp = nullptr; int tgt = 0;
      if (l < 16){ fp = fown + l*16; tgt = t; }                      // own h[t-1]
      else if (l < 32 && layer == 1){ fp = fprod + (l-16)*16; tgt = t + 1; } // h0[t]
      if (fp){
        while (ld_flag(fp) < tgt) __builtin_amdgcn_s_sleep(1);
      }
    }
    __syncthreads();

    f32x4 acc = {0.f, 0.f, 0.f, 0.f};
    bf16x8 st[16];
    if (layer == 0){
      const int pos = dir ? (129 - t) : t;
      const unsigned short* xa = x + ((size_t)lr*130 + pos)*256 + lk*8;
      #pragma unroll
      for (int i = 0; i < 8; ++i){
        bf16x8 a = *(const bf16x8*)(xa + i*32);
        acc = __builtin_amdgcn_mfma_f32_16x16x32_bf16(a, kreg[i], acc, 0, 0, 0);
      }
      if (t > 0){
        const unsigned short* ha = h0 + ((size_t)(t-1)*16 + lr)*512 + lk*8;
        LD16(st, ha);
        WAIT_VM0();
        #pragma unroll
        for (int i = 0; i < 16; ++i)
          acc = __builtin_amdgcn_mfma_f32_16x16x32_bf16(st[i], wreg[i], acc, 0, 0, 0);
      }
    } else {
      const unsigned short* xa = h0 + ((size_t)t*16 + lr)*512 + lk*8;
      LD16(st, xa);
      WAIT_VM0();
      #pragma unroll
      for (int i = 0; i < 16; ++i)
        acc = __builtin_amdgcn_mfma_f32_16x16x32_bf16(st[i], kreg[i], acc, 0, 0, 0);
      if (t > 0){
        const int prow = dir ? (128 - t) : (t - 1);
        const unsigned short* ha = aproj + ((size_t)lr*128 + prow)*1024 + dir*512 + lk*8;
        LD16(st, ha);
        WAIT_VM0();
        #pragma unroll
        for (int i = 0; i < 16; ++i)
          acc = __builtin_amdgcn_mfma_f32_16x16x32_bf16(st[i], wreg[i], acc, 0, 0, 0);
      }
    }
    // C-frag: col = lane&15, row = (lane>>4)*4 + r  (verified m89/m91)
    #pragma unroll
    for (int r = 0; r < 4; ++r) z_lds[gate][lk*4 + r][half*16 + lr] = acc[r];
    __syncthreads();
    {
      const float zi = z_lds[0][gb][gu] + bzi;
      const float zf = z_lds[1][gb][gu] + bzf;
      const float zc = z_lds[2][gb][gu] + bzc;
      const float zo = z_lds[3][gb][gu] + bzo;
      const float iv = 1.f / (1.f + expf(-zi));
      const float fv = 1.f / (1.f + expf(-zf));
      const float ov = 1.f / (1.f + expf(-zo));
      const float gv = tanhf(zc);
      float cn = fv*c_reg + iv*gv;
      float hn = ov*tanhf(cn);
      const int pos = dir ? (129 - t) : t;
      if (mask_s[gb*130 + pos] == 0){ cn = c_reg; hn = h_reg; }
      c_reg = cn; h_reg = hn;
      const unsigned short hb = f2bf(hn);
      if (layer == 0){
        unsigned short* p = h0 + ((size_t)t*16 + gb)*512 + u0 + gu;
        BYPASS_ST_SHORT(p, (unsigned)hb);
      } else {
        const int row = dir ? (127 - t) : t;
        unsigned short* p = aproj + ((size_t)gb*128 + row)*1024 + dir*512 + u0 + gu;
        BYPASS_ST_SHORT(p, (unsigned)hb);
      }
    }
    // ---- release: drain own bypass stores in EVERY wave, then one flag store ----
    asm volatile("s_waitcnt vmcnt(0)" ::: "memory");
    __syncthreads();
    if (tid == 0){
      int v = t + 1;
      asm volatile("global_store_dword %0, %1, off sc0 sc1" :: "v"(fself), "v"(v) : "memory");
    }
  }
}

// ---------------- bf16 MFMA GEMM: C[M,N] = A[M,K] * Bt[N,K]^T + bias ----------------
// 128x128 tile, BK=32, 4 waves (2x2 of 64x64). Staging via global_load_lds width=16:
// linear LDS dest + pre-swizzled global source; reads apply the same XOR swizzle.
__global__ __launch_bounds__(256) void gemm_bf16(
    const unsigned short* __restrict__ A, const unsigned short* __restrict__ Bt,
    const float* __restrict__ bias, float* __restrict__ C,
    int M, int N, int K)
{
  __shared__ unsigned short lA[128*32], lB[128*32];
  const int tid = threadIdx.x;
  const int w = tid >> 6, l = tid & 63;
  const int wr = w >> 1, wc = w & 1;
  const int lr = l & 15, lk = l >> 4;
  const int brow = blockIdx.y * 128, bcol = blockIdx.x * 128;
  f32x4 acc[4][4] = {};
  for (int k0 = 0; k0 < K; k0 += 32){
    __syncthreads();
    #pragma unroll
    for (int j = 0; j < 2; ++j){
      const int base = w*2048 + j*1024;          // wave-uniform LDS byte base
      const int L = base + l*16;                 // this lane's linear LDS slot
      const int Lg = L ^ (((L >> 7) & 3) << 4);  // pre-swizzled (involutive) source
      const int row = Lg >> 6, kb = Lg & 63;
      gload_lds16((const char*)(A + (size_t)(brow+row)*K + k0) + kb, (char*)lA + base);
      gload_lds16((const char*)(Bt + (size_t)(bcol+row)*K + k0) + kb, (char*)lB + base);
    }
    __syncthreads();
    bf16x8 af[4], bfr[4];
    #pragma unroll
    for (int m = 0; m < 4; ++m){
      const int L = (wr*64 + m*16 + lr)*64 + lk*16;
      const int sp = L ^ (((L >> 7) & 3) << 4);
      af[m] = *(const bf16x8*)((char*)lA + sp);
    }
    #pragma unroll
    for (int n = 0; n < 4; ++n){
      const int L = (wc*64 + n*16 + lr)*64 + lk*16;
      const int sp = L ^ (((L >> 7) & 3) << 4);
      bfr[n] = *(const bf16x8*)((char*)lB + sp);
    }
    #pragma unroll
    for (int m = 0; m < 4; ++m)
      #pragma unroll
      for (int n = 0; n < 4; ++n)
        acc[m][n] = __builtin_amdgcn_mfma_f32_16x16x32_bf16(af[m], bfr[n], acc[m][n], 0, 0, 0);
  }
  #pragma unroll
  for (int m = 0; m < 4; ++m){
    #pragma unroll
    for (int n = 0; n < 4; ++n){
      const int col = bcol + wc*64 + n*16 + lr;
      const float bv = bias[col];
      const int row0 = brow + wr*64 + m*16 + lk*4;
      #pragma unroll
      for (int r = 0; r < 4; ++r)
        C[(size_t)(row0 + r)*N + col] = acc[m][n][r] + bv;
    }
  }
}

extern "C" void kernel_launch(void* const* d_in, const int* in_sizes, int n_in,
                              void* d_out, int out_size, void* d_ws, size_t ws_size,
                              hipStream_t stream){
  (void)in_sizes; (void)n_in; (void)out_size; (void)ws_size;
  const int*   seqs = (const int*)d_in[0];
  const float* emb  = (const float*)d_in[1];
  const float* fk0  = (const float*)d_in[2];
  const float* fr0  = (const float*)d_in[3];
  const float* fb0  = (const float*)d_in[4];
  const float* fk1  = (const float*)d_in[5];
  const float* fr1  = (const float*)d_in[6];
  const float* fb1  = (const float*)d_in[7];
  const float* bk0  = (const float*)d_in[8];
  const float* br0  = (const float*)d_in[9];
  const float* bb0  = (const float*)d_in[10];
  const float* bk1  = (const float*)d_in[11];
  const float* br1  = (const float*)d_in[12];
  const float* bb1  = (const float*)d_in[13];
  const float* Wp   = (const float*)d_in[14];
  const float* bp   = (const float*)d_in[15];
  float* out = (float*)d_out;

  char* ws = (char*)d_ws;
  size_t off = 0;
  auto alloc = [&](size_t b){ size_t o = off; off += (b + 255) & ~(size_t)255; return o; };
  int* flags            = (int*)(ws + alloc(4096));
  unsigned short* x     = (unsigned short*)(ws + alloc((size_t)16*130*256*2));
  int* mask             = (int*)(ws + alloc((size_t)16*130*4));
  unsigned short* fk0T  = (unsigned short*)(ws + alloc((size_t)2048*256*2));
  unsigned short* fr0T  = (unsigned short*)(ws + alloc((size_t)2048*512*2));
  unsigned short* fk1T  = (unsigned short*)(ws + alloc((size_t)2048*512*2));
  unsigned short* fr1T  = (unsigned short*)(ws + alloc((size_t)2048*512*2));
  unsigned short* bk0T  = (unsigned short*)(ws + alloc((size_t)2048*256*2));
  unsigned short* br0T  = (unsigned short*)(ws + alloc((size_t)2048*512*2));
  unsigned short* bk1T  = (unsigned short*)(ws + alloc((size_t)2048*512*2));
  unsigned short* br1T  = (unsigned short*)(ws + alloc((size_t)2048*512*2));
  unsigned short* h0f   = (unsigned short*)(ws + alloc((size_t)128*16*512*2));
  unsigned short* h0b   = (unsigned short*)(ws + alloc((size_t)128*16*512*2));
  unsigned short* aproj = (unsigned short*)(ws + alloc((size_t)2048*1024*2));
  unsigned short* WpT   = (unsigned short*)(ws + alloc((size_t)32000*1024*2));

  embed_kernel<<<dim3(130,16), 64, 0, stream>>>(seqs, emb, x, mask, flags);

  dim3 tb(32, 8);
  transpose_bf16<<<dim3(64, 8),   tb, 0, stream>>>(fk0, fk0T, 256, 2048);
  transpose_bf16<<<dim3(64, 16),  tb, 0, stream>>>(fr0, fr0T, 512, 2048);
  transpose_bf16<<<dim3(64, 16),  tb, 0, stream>>>(fk1, fk1T, 512, 2048);
  transpose_bf16<<<dim3(64, 16),  tb, 0, stream>>>(fr1, fr1T, 512, 2048);
  transpose_bf16<<<dim3(64, 8),   tb, 0, stream>>>(bk0, bk0T, 256, 2048);
  transpose_bf16<<<dim3(64, 16),  tb, 0, stream>>>(br0, br0T, 512, 2048);
  transpose_bf16<<<dim3(64, 16),  tb, 0, stream>>>(bk1, bk1T, 512, 2048);
  transpose_bf16<<<dim3(64, 16),  tb, 0, stream>>>(br1, br1T, 512, 2048);
  transpose_bf16<<<dim3(1000, 32), tb, 0, stream>>>(Wp, WpT, 1024, 32000);

  lstm_coop<<<64, 512, 0, stream>>>(x, mask,
      fk0T, fr0T, fk1T, fr1T, bk0T, br0T, bk1T, br1T,
      fb0, fb1, bb0, bb1, h0f, h0b, aproj, flags);

  gemm_bf16<<<dim3(250, 16), 256, 0, stream>>>(aproj, WpT, bp, out, 2048, 32000, 1024);
}